// Round 7
// baseline (420.665 us; speedup 1.0000x reference)
//
#include <hip/hip_runtime.h>
#include <hip/hip_bf16.h>

// MetaQDA MAP. D=640, C=64, N=1024, Q=2048, REG=0.3.
// sigma_c*denom = L L^T + U_c J_c U_c^T (rank 18) => Woodbury.
// Round 7: deterministic setup (ordered scan, no atomics) so graph replays
// are bit-identical; f32 Gram from Ytout + f64 pivoted GJ in k_inv18;
// G GEMM back to Q rows.

#define D 640
#define C 64
#define NSUP 1024
#define Q 2048
#define KMAX 16
#define R18 18           // Woodbury rank: 1 (m) + 16 (x) + 1 (mu)
#define VROWS (C * R18)  // 1152
#define YROWS 3137       // 2048 Xq + 1024 X + 1 m + 64 mu
#define YPAD 3200
#define NEXT 704         // 640 tilde cols + 64 ip0 cols

typedef __attribute__((ext_vector_type(8))) short bf16x8;
typedef __attribute__((ext_vector_type(4))) float floatx4;

__device__ __forceinline__ unsigned short f2bf(float x) {
    unsigned int u = __float_as_uint(x);
    unsigned int r = u + 0x7FFFu + ((u >> 16) & 1u);
    return (unsigned short)(r >> 16);
}

// ---------------- setup: DETERMINISTIC class lists, scalars, rowmap ------
__global__ void k_setup(const int* __restrict__ y, const float* __restrict__ kappa,
                        const float* __restrict__ nu, const float* __restrict__ diag,
                        int* __restrict__ cnt, int* __restrict__ idx,
                        float* __restrict__ sc, float* __restrict__ rd,
                        int* __restrict__ rowmap) {
    __shared__ int sidx[C * KMAX];
    __shared__ int lcs[C];
    int tid = threadIdx.x;
    if (tid < C) {
        int k = 0;
        for (int n = 0; n < NSUP; ++n) {          // ordered scan: deterministic,
            if (y[n] == tid && k < KMAX) {        // ascending (matches ref order)
                sidx[tid * KMAX + k] = n; ++k;
            }
        }
        lcs[tid] = k;
        cnt[tid] = k;
    }
    __syncthreads();
    for (int i = tid; i < C * KMAX; i += 256) idx[i] = sidx[i];
    for (int d = tid; d < D; d += 256) rd[d] = 1.0f / fabsf(diag[d]);
    if (tid < C) {
        int n = lcs[tid];
        float kap = fabsf(kappa[0]) + 1e-6f;
        float nuv = fmaxf(nu[0], (float)(D - 1) + 1e-6f);
        float Ncf = (float)n;
        sc[64 + tid]  = Ncf / (kap + Ncf);            // w_c
        sc[128 + tid] = nuv + Ncf + (float)(D + 2);   // denom_c
        sc[192 + tid] = -1.0f / (kap + Ncf);          // J^{-1} last diag
        if (tid == 0) { sc[0] = kap; sc[1] = nuv; }
    }
    __syncthreads();
    for (int i = tid; i < VROWS; i += 256) {
        int c = i / R18, j = i - c * R18;
        int nc = lcs[c];
        int rm;
        if (j == 0) rm = Q + NSUP;                       // m~
        else if (j <= KMAX) rm = (j - 1 < nc) ? Q + sidx[c * KMAX + j - 1] : -1;
        else rm = Q + NSUP + 1 + c;                      // mu~
        rowmap[i] = rm;
    }
}

// ---------------- mu[c][d] = (1-w)*m + w*mean_c --------------------------
__global__ void k_mu(const float* __restrict__ X, const float* __restrict__ m,
                     const int* __restrict__ cnt, const int* __restrict__ idx,
                     const float* __restrict__ sc, float* __restrict__ mu) {
    int c = blockIdx.x;
    int d = blockIdx.y * 128 + threadIdx.x;
    int n = cnt[c];
    float s = 0.f;
    for (int k = 0; k < n; ++k) s += X[(size_t)idx[c * KMAX + k] * D + d];
    float w = sc[64 + c];
    float mean = (n > 0) ? s / (float)n : 0.f;
    mu[(size_t)c * D + d] = (1.f - w) * m[d] + w * mean;
}

// ---------------- Dinv: invert 5 diagonal 128x128 blocks into Linv -------
__global__ void k_dinv(const float* __restrict__ tlow, const float* __restrict__ rd,
                       float* __restrict__ Linv) {
    __shared__ float Lst[128 * 128];
    int tid = threadIdx.x;
    int b = blockIdx.x >> 5;
    int j = ((blockIdx.x & 31) << 2) + (tid >> 6);
    int lane = tid & 63;
    int bB = b * 128;
    for (int e = tid; e < 128 * 128; e += 256) {
        int c = e & 127, r = e >> 7;
        float v;
        if (r == c) v = 1.0f;
        else if (r > c) v = rd[bB + r] * tlow[(size_t)(bB + r) * D + bB + c];
        else v = 0.f;
        Lst[c * 128 + (r ^ (c & 63))] = v;
    }
    __syncthreads();
    float rd0 = rd[bB + lane], rd1 = rd[bB + 64 + lane];
    float acc0 = 0.f, acc1 = 0.f, zz0 = 0.f, zz1 = 0.f;
    for (int i = j; i < 128; ++i) {
        int ri = i >> 6, il = i & 63;
        float av = (ri == 0) ? acc0 : acc1;
        float ai = __shfl(av, il);
        float zi = (i == j) ? __shfl((ri == 0) ? rd0 : rd1, il) : -ai;
        int sw = i & 63;
        float l0 = Lst[i * 128 + (lane ^ sw)];
        float l1 = Lst[i * 128 + 64 + (lane ^ sw)];
        if (lane > i) acc0 += l0 * zi;
        if (64 + lane > i) acc1 += l1 * zi;
        if (lane == i) zz0 = zi;
        if (64 + lane == i) zz1 = zi;
    }
    Linv[(size_t)(bB + lane) * D + bB + j] = zz0;
    Linv[(size_t)(bB + 64 + lane) * D + bB + j] = zz1;
}

// ---------------- Lhat_ik = Dinv_i * L_ik (strict-lower blocks) ----------
__global__ void k_lhat(const float* __restrict__ tlow, const float* __restrict__ Linv,
                       float* __restrict__ Lhat) {
    const int bi_tab[10] = {1, 2, 2, 3, 3, 3, 4, 4, 4, 4};
    const int bk_tab[10] = {0, 0, 1, 0, 1, 2, 0, 1, 2, 3};
    int p = blockIdx.y;
    int bi = bi_tab[p], bk = bk_tab[p];
    int tid = threadIdx.x;
    int c = tid & 127;
    int r = (blockIdx.x << 1) + (tid >> 7);
    const float* drow = Linv + (size_t)(bi * 128 + r) * D + bi * 128;
    const float* lcol = tlow + (size_t)(bi * 128) * D + bk * 128 + c;
    float s = 0.f;
#pragma unroll 4
    for (int t = 0; t < 128; ++t) s += drow[t] * lcol[(size_t)t * D];
    Lhat[(size_t)(bi * 128 + r) * D + bk * 128 + c] = s;
}

// ---------------- Linv off-diag: fused strip recurrence ------------------
__global__ __launch_bounds__(256) void k_linv_fill(const float* __restrict__ Lhat,
                                                   float* __restrict__ Linv) {
    __shared__ __align__(16) float S[4][128][20];   // 40 KB
    __shared__ __align__(16) float LhT[32][132];    // 17 KB
    int tid = threadIdx.x;
    int b = blockIdx.x >> 3, strip = blockIdx.x & 7;
    int bB = b * 128, cB = bB + strip * 16;
    int ty = tid >> 2, tx = tid & 3;
    {
        int r = tid >> 1, c0 = (tid & 1) * 8;
        const float* src = Linv + (size_t)(bB + r) * D + cB + c0;
#pragma unroll
        for (int e = 0; e < 8; ++e) S[0][r][c0 + e] = src[e];
    }
    __syncthreads();
    for (int i = b + 1; i <= 4; ++i) {
        float acc[2][4] = {};
        for (int j = b; j < i; ++j) {
            for (int k0 = 0; k0 < 128; k0 += 32) {
                __syncthreads();
                {
                    int r = tid >> 1, kk = (tid & 1) * 16;
                    const float* src = Lhat + (size_t)(i * 128 + r) * D + j * 128 + k0 + kk;
#pragma unroll
                    for (int e = 0; e < 16; ++e) LhT[kk + e][r] = src[e];
                }
                __syncthreads();
#pragma unroll 4
                for (int k = 0; k < 32; ++k) {
                    float a0 = LhT[k][ty * 2], a1 = LhT[k][ty * 2 + 1];
                    float4 bv = *(const float4*)&S[j - b][k0 + k][tx * 4];
                    acc[0][0] += a0 * bv.x; acc[0][1] += a0 * bv.y;
                    acc[0][2] += a0 * bv.z; acc[0][3] += a0 * bv.w;
                    acc[1][0] += a1 * bv.x; acc[1][1] += a1 * bv.y;
                    acc[1][2] += a1 * bv.z; acc[1][3] += a1 * bv.w;
                }
            }
        }
        int si = i - b;
#pragma unroll
        for (int rr = 0; rr < 2; ++rr) {
            int r = ty * 2 + rr;
#pragma unroll
            for (int cc = 0; cc < 4; ++cc) {
                float v = -acc[rr][cc];
                if (si <= 3) S[si][r][tx * 4 + cc] = v;
                Linv[(size_t)(i * 128 + r) * D + cB + tx * 4 + cc] = v;
            }
        }
    }
}

// ---------------- pack A-side: [Xq; X; m; mu] -> hi/lo bf16 [3200x640] ---
__global__ void k_pack_src(const float* __restrict__ Xq, const float* __restrict__ X,
                           const float* __restrict__ m, const float* __restrict__ mu,
                           unsigned short* __restrict__ hi, unsigned short* __restrict__ lo) {
    int gid = blockIdx.x * 256 + threadIdx.x;
    int row = gid / 160, c = (gid - row * 160) * 4;
    if (row >= YPAD) return;
    float4 v = {0.f, 0.f, 0.f, 0.f};
    if (row < Q) v = *(const float4*)(Xq + (size_t)row * D + c);
    else if (row < Q + NSUP) v = *(const float4*)(X + (size_t)(row - Q) * D + c);
    else if (row == Q + NSUP) v = *(const float4*)(m + c);
    else if (row < YROWS) v = *(const float4*)(mu + (size_t)(row - (Q + NSUP + 1)) * D + c);
    float vv[4] = {v.x, v.y, v.z, v.w};
    ushort4 h, l;
    unsigned short* hp = (unsigned short*)&h;
    unsigned short* lp = (unsigned short*)&l;
#pragma unroll
    for (int i = 0; i < 4; ++i) {
        unsigned short hb = f2bf(vv[i]);
        float hf = __uint_as_float((unsigned int)hb << 16);
        hp[i] = hb;
        lp[i] = f2bf(vv[i] - hf);
    }
    *(ushort4*)(hi + (size_t)row * D + c) = h;
    *(ushort4*)(lo + (size_t)row * D + c) = l;
}

// ---------------- pack B-side: [Linv (upper masked); mu] -> [704x640] ----
__global__ void k_pack_b(const float* __restrict__ Linv, const float* __restrict__ mu,
                         unsigned short* __restrict__ hi, unsigned short* __restrict__ lo) {
    int gid = blockIdx.x * 256 + threadIdx.x;
    int row = gid / 160, c = (gid - row * 160) * 4;
    if (row >= NEXT) return;
    float4 v;
    if (row < D) v = *(const float4*)(Linv + (size_t)row * D + c);
    else v = *(const float4*)(mu + (size_t)(row - D) * D + c);
    float vv[4] = {v.x, v.y, v.z, v.w};
    ushort4 h, l;
    unsigned short* hp = (unsigned short*)&h;
    unsigned short* lp = (unsigned short*)&l;
#pragma unroll
    for (int i = 0; i < 4; ++i) {
        float x = (row < D && c + i > row) ? 0.f : vv[i];   // strict upper = 0
        unsigned short hb = f2bf(x);
        float hf = __uint_as_float((unsigned int)hb << 16);
        hp[i] = hb;
        lp[i] = f2bf(x - hf);
    }
    *(ushort4*)(hi + (size_t)row * D + c) = h;
    *(ushort4*)(lo + (size_t)row * D + c) = l;
}

// ---------------- pack Yt (f32, ld=704, cols 0..639) -> hi/lo ------------
__global__ void k_pack_t(const float* __restrict__ Yt,
                         unsigned short* __restrict__ hi, unsigned short* __restrict__ lo) {
    int gid = blockIdx.x * 256 + threadIdx.x;
    int row = gid / 160, c = (gid - row * 160) * 4;
    if (row >= YPAD) return;
    float4 v = *(const float4*)(Yt + (size_t)row * NEXT + c);
    float vv[4] = {v.x, v.y, v.z, v.w};
    ushort4 h, l;
    unsigned short* hp = (unsigned short*)&h;
    unsigned short* lp = (unsigned short*)&l;
#pragma unroll
    for (int i = 0; i < 4; ++i) {
        unsigned short hb = f2bf(vv[i]);
        float hf = __uint_as_float((unsigned int)hb << 16);
        hp[i] = hb;
        lp[i] = f2bf(vv[i] - hf);
    }
    *(ushort4*)(hi + (size_t)row * D + c) = h;
    *(ushort4*)(lo + (size_t)row * D + c) = l;
}

// ---------------- split-bf16 MFMA NT GEMM, 64x64 tile --------------------
__global__ __launch_bounds__(256) void k_mfma_nt(
        const unsigned short* __restrict__ Ah, const unsigned short* __restrict__ Al,
        const unsigned short* __restrict__ Bh, const unsigned short* __restrict__ Bl,
        const int* __restrict__ rowmap, float* __restrict__ Out,
        int M, int N, int ldo) {
    __shared__ unsigned short Ah_s[64 * 32], Al_s[64 * 32];
    __shared__ unsigned short Bh_s[64 * 32], Bl_s[64 * 32];
    int tid = threadIdx.x;
    int rowBase = blockIdx.y * 64, colBase = blockIdx.x * 64;
    int r = tid >> 2, e = (tid & 3) << 3;
    int gr = rowBase + r;
    int gc = colBase + r;
    int br = (gc < N) ? (rowmap ? rowmap[gc] : gc) : -1;
    bool aok = (gr < M);
    int w = tid >> 6, lane = tid & 63, q = lane >> 4, lr = lane & 15;
    int aoff = (16 * w + lr) * 32 + q * 8;
    const uint4 z4 = {0u, 0u, 0u, 0u};
    floatx4 acc[4] = {{0.f, 0.f, 0.f, 0.f}, {0.f, 0.f, 0.f, 0.f},
                      {0.f, 0.f, 0.f, 0.f}, {0.f, 0.f, 0.f, 0.f}};
    for (int kk = 0; kk < D; kk += 32) {
        uint4 vah = aok ? *(const uint4*)(Ah + (size_t)gr * D + kk + e) : z4;
        uint4 val = aok ? *(const uint4*)(Al + (size_t)gr * D + kk + e) : z4;
        uint4 vbh = (br >= 0) ? *(const uint4*)(Bh + (size_t)br * D + kk + e) : z4;
        uint4 vbl = (br >= 0) ? *(const uint4*)(Bl + (size_t)br * D + kk + e) : z4;
        __syncthreads();
        *(uint4*)(Ah_s + r * 32 + e) = vah;
        *(uint4*)(Al_s + r * 32 + e) = val;
        *(uint4*)(Bh_s + r * 32 + e) = vbh;
        *(uint4*)(Bl_s + r * 32 + e) = vbl;
        __syncthreads();
        bf16x8 ah = *(const bf16x8*)(Ah_s + aoff);
        bf16x8 al = *(const bf16x8*)(Al_s + aoff);
#pragma unroll
        for (int tt = 0; tt < 4; ++tt) {
            int boff = (16 * tt + lr) * 32 + q * 8;
            bf16x8 bh = *(const bf16x8*)(Bh_s + boff);
            bf16x8 bl = *(const bf16x8*)(Bl_s + boff);
            acc[tt] = __builtin_amdgcn_mfma_f32_16x16x32_bf16(ah, bh, acc[tt], 0, 0, 0);
            acc[tt] = __builtin_amdgcn_mfma_f32_16x16x32_bf16(ah, bl, acc[tt], 0, 0, 0);
            acc[tt] = __builtin_amdgcn_mfma_f32_16x16x32_bf16(al, bh, acc[tt], 0, 0, 0);
        }
    }
#pragma unroll
    for (int tt = 0; tt < 4; ++tt) {
        int gc2 = colBase + 16 * tt + lr;
#pragma unroll
        for (int rg = 0; rg < 4; ++rg) {
            int gr2 = rowBase + 16 * w + q * 4 + rg;
            if (gr2 < M && gc2 < N) Out[(size_t)gr2 * ldo + gc2] = acc[tt][rg];
        }
    }
}

// ---------------- row norms (one wave per row, Q rows) -------------------
__global__ void k_rownorm(const float* __restrict__ A, int ld, float* __restrict__ out) {
    int gw = (blockIdx.x * 256 + threadIdx.x) >> 6;
    int lane = threadIdx.x & 63;
    const float* row = A + (size_t)gw * ld;
    float s = 0.f;
    for (int d = lane; d < D; d += 64) { float v = row[d]; s += v * v; }
#pragma unroll
    for (int off = 32; off; off >>= 1) s += __shfl_xor(s, off);
    if (lane == 0) out[gw] = s;
}

// ---------------- extract ip0 cols (640..703) of Ytout -------------------
__global__ void k_ip0ext(const float* __restrict__ Yt, float* __restrict__ ip0) {
    int gid = blockIdx.x * 256 + threadIdx.x;   // Q*C
    int q = gid >> 6, c = gid & 63;
    ip0[gid] = Yt[(size_t)q * NEXT + D + c];
}

// ---------------- per-class: f32 Gram from Yt + f64 pivoted GJ -----------
__global__ __launch_bounds__(256) void k_inv18(const float* __restrict__ Yt,
        const int* __restrict__ rowmap, const float* __restrict__ mu,
        const float* __restrict__ sc, float* __restrict__ h,
        float* __restrict__ btil, float* __restrict__ b0,
        float* __restrict__ kinv) {
    __shared__ float sv[R18][D + 4];                 // 46 KB
    __shared__ float gram[R18][R18 + 1];
    __shared__ double aug[R18][2 * R18 + 1];         // 5.3 KB
    __shared__ double fcol[R18];
    __shared__ int piv_s;
    int c = blockIdx.x, tid = threadIdx.x;
    for (int i = tid; i < R18 * D; i += 256) {
        int r = i / D, d = i - r * D;
        int rm = rowmap[c * R18 + r];
        sv[r][d] = (rm >= 0) ? Yt[(size_t)rm * NEXT + d] : 0.f;
    }
    __syncthreads();
    int wv = tid >> 6, lane = tid & 63;
    for (int p = wv; p < 171; p += 4) {
        int i = 0, rem = p;
        while (rem >= R18 - i) { rem -= R18 - i; ++i; }
        int j = i + rem;
        float s = 0.f;
        for (int d = lane; d < D; d += 64) s += sv[i][d] * sv[j][d];
#pragma unroll
        for (int off = 32; off; off >>= 1) s += __shfl_xor(s, off);
        if (lane == 0) { gram[i][j] = s; gram[j][i] = s; }
    }
    if (wv == 3) {      // b0 = ||mu_c||^2
        float s0 = 0.f;
        for (int d = lane; d < D; d += 64) { float v = mu[(size_t)c * D + d]; s0 += v * v; }
#pragma unroll
        for (int off = 32; off; off >>= 1) s0 += __shfl_xor(s0, off);
        if (lane == 0) b0[c] = s0;
    }
    __syncthreads();
    if (tid < R18) h[c * R18 + tid] = gram[tid][R18 - 1];
    if (tid == 0) btil[c] = gram[R18 - 1][R18 - 1];
    // build augmented K | I in f64
    for (int e = tid; e < R18 * 2 * R18; e += 256) {
        int i = e / (2 * R18), j = e - i * (2 * R18);
        double v;
        if (j < R18) {
            v = (double)gram[i][j];
            if (i == j) {
                if (i == 0) v += 1.0 / (double)sc[0];
                else if (i <= KMAX) v += 1.0;
                else v += (double)sc[192 + c];
            }
        } else v = (j - R18 == i) ? 1.0 : 0.0;
        aug[i][j] = v;
    }
    __syncthreads();
    for (int p = 0; p < R18; ++p) {
        if (tid < 64) {   // parallel pivot argmax (wave 0)
            double v = (tid >= p && tid < R18) ? fabs(aug[tid][p]) : -1.0;
            int bi = tid;
#pragma unroll
            for (int off = 32; off; off >>= 1) {
                double ov = __shfl_xor(v, off);
                int oi = __shfl_xor(bi, off);
                if (ov > v || (ov == v && oi < bi)) { v = ov; bi = oi; }
            }
            if (tid == 0) piv_s = bi;
        }
        __syncthreads();
        int piv = piv_s;
        if (piv != p && tid < 2 * R18) {
            double t = aug[p][tid]; aug[p][tid] = aug[piv][tid]; aug[piv][tid] = t;
        }
        __syncthreads();
        double rcp = 1.0 / aug[p][p];
        __syncthreads();
        if (tid < 2 * R18) aug[p][tid] *= rcp;
        if (tid < R18 && tid != p) fcol[tid] = aug[tid][p];
        __syncthreads();
        for (int e = tid; e < R18 * 2 * R18; e += 256) {
            int r = e / (2 * R18), j = e - r * (2 * R18);
            if (r != p) aug[r][j] -= fcol[r] * aug[p][j];
        }
        __syncthreads();
    }
    for (int e = tid; e < R18 * R18; e += 256)
        kinv[(size_t)c * R18 * R18 + e] = (float)aug[e / R18][R18 + e % R18];
}

// ---------------- epilogue ----------------------------------------------
__global__ void k_epi(const float* __restrict__ G, const float* __restrict__ ip0b,
                      const float* __restrict__ at, const float* __restrict__ a0,
                      const float* __restrict__ h, const float* __restrict__ btil,
                      const float* __restrict__ b0, const float* __restrict__ kinv,
                      const float* __restrict__ sc, float* __restrict__ out) {
    __shared__ float lk[R18 * R18], lh[R18];
    __shared__ float ldn, lbt, lb0;
    int c = blockIdx.x, tid = threadIdx.x;
    for (int i = tid; i < R18 * R18; i += 256) lk[i] = kinv[(size_t)c * R18 * R18 + i];
    if (tid < R18) lh[tid] = h[c * R18 + tid];
    if (tid == 0) { ldn = sc[128 + c]; lbt = btil[c]; lb0 = b0[c]; }
    __syncthreads();
    int q = blockIdx.y * 256 + tid;
    const float* Gr = G + (size_t)q * VROWS + c * R18;
    float g[R18];
#pragma unroll
    for (int j = 0; j < R18; ++j) g[j] = Gr[j];
    float ipt = g[R18 - 1];
#pragma unroll
    for (int j = 0; j < R18; ++j) g[j] -= lh[j];
    float corr = 0.f;
#pragma unroll
    for (int i = 0; i < R18; ++i) {
        float s = 0.f;
#pragma unroll
        for (int j = 0; j < R18; ++j) s += lk[i * R18 + j] * g[j];
        corr += g[i] * s;
    }
    float ip0 = ip0b[(size_t)q * C + c];
    float tt = at[q] - 2.f * ipt + lbt;
    float t0 = a0[q] - 2.f * ip0 + lb0;
    out[(size_t)q * C + c] = -(0.7f * ldn * (tt - corr) + 0.3f * t0);
}

extern "C" void kernel_launch(void* const* d_in, const int* in_sizes, int n_in,
                              void* d_out, int out_size, void* d_ws, size_t ws_size,
                              hipStream_t stream) {
    const float* X     = (const float*)d_in[0];
    const int*   y     = (const int*)d_in[1];
    const float* Xq    = (const float*)d_in[2];
    const float* m     = (const float*)d_in[3];
    const float* kappa = (const float*)d_in[4];
    const float* nu    = (const float*)d_in[5];
    const float* tdiag = (const float*)d_in[6];
    const float* tlow  = (const float*)d_in[7];
    float* out = (float*)d_out;

    char* w = (char*)d_ws;
    auto alloc = [&](size_t bytes) {
        char* p = w;
        w += (bytes + 255) & ~(size_t)255;
        return p;
    };
    int*   cnt    = (int*)alloc(C * 4);
    int*   idx    = (int*)alloc(C * KMAX * 4);
    int*   rowmap = (int*)alloc(VROWS * 4);
    float* sc     = (float*)alloc(256 * 4);
    float* rd     = (float*)alloc(D * 4);
    float* mu     = (float*)alloc((size_t)C * D * 4);
    float* at     = (float*)alloc(Q * 4);
    float* a0     = (float*)alloc(Q * 4);
    float* h      = (float*)alloc(C * R18 * 4);
    float* btil   = (float*)alloc(C * 4);
    float* b0     = (float*)alloc(C * 4);
    float* kinv   = (float*)alloc((size_t)C * R18 * R18 * 4);
    float* ip0b   = (float*)alloc((size_t)Q * C * 4);                  // 0.5 MB
    unsigned short* Th = (unsigned short*)alloc((size_t)YPAD * D * 2); // 4.1 MB
    unsigned short* Tl = (unsigned short*)alloc((size_t)YPAD * D * 2);
    unsigned short* Bh = (unsigned short*)alloc((size_t)NEXT * D * 2); // 0.9 MB
    unsigned short* Bl = (unsigned short*)alloc((size_t)NEXT * D * 2);
    // overlap region: [Linv|Lhat|Ah|Al|Ytout] all dead before G is written.
    char* region = alloc((size_t)20480000);
    float* Linv  = (float*)(region);                    // 1,638,400 B
    float* Lhat  = (float*)(region + 1638400);          // 1,638,400 B
    unsigned short* Ah = (unsigned short*)(region + 3276800);   // 4,096,000 B
    unsigned short* Al = (unsigned short*)(region + 7372800);   // 4,096,000 B
    float* Ytout = (float*)(region + 11468800);         // 9,011,200 B
    float* G     = (float*)(region);                    // 9,437,184 B

    k_setup<<<1, 256, 0, stream>>>(y, kappa, nu, tdiag, cnt, idx, sc, rd, rowmap);
    k_mu<<<dim3(C, D / 128), 128, 0, stream>>>(X, m, cnt, idx, sc, mu);
    k_dinv<<<160, 256, 0, stream>>>(tlow, rd, Linv);
    k_lhat<<<dim3(64, 10), 256, 0, stream>>>(tlow, Linv, Lhat);
    k_linv_fill<<<32, 256, 0, stream>>>(Lhat, Linv);
    k_pack_src<<<(YPAD * 160 + 255) / 256, 256, 0, stream>>>(Xq, X, m, mu, Ah, Al);
    k_pack_b<<<(NEXT * 160 + 255) / 256, 256, 0, stream>>>(Linv, mu, Bh, Bl);
    k_rownorm<<<Q / 4, 256, 0, stream>>>(Xq, D, a0);
    // Ytout[r][0:640] = tilde rows; [640:704] = x_r . mu_c
    k_mfma_nt<<<dim3(NEXT / 64, YPAD / 64), 256, 0, stream>>>(
        Ah, Al, Bh, Bl, nullptr, Ytout, YPAD, NEXT, NEXT);
    k_rownorm<<<Q / 4, 256, 0, stream>>>(Ytout, NEXT, at);
    k_inv18<<<C, 256, 0, stream>>>(Ytout, rowmap, mu, sc, h, btil, b0, kinv);
    k_pack_t<<<(YPAD * 160 + 255) / 256, 256, 0, stream>>>(Ytout, Th, Tl);
    k_ip0ext<<<(Q * C) / 256, 256, 0, stream>>>(Ytout, ip0b);
    // G[q][c*18+j] = x~q . v~_{c,j}  (Q rows only)
    k_mfma_nt<<<dim3(VROWS / 64, Q / 64), 256, 0, stream>>>(
        Th, Tl, Th, Tl, rowmap, G, Q, VROWS, VROWS);
    k_epi<<<dim3(C, Q / 256), 256, 0, stream>>>(G, ip0b, at, a0, h, btil, b0, kinv, sc, out);
}

// Round 9
// 407.121 us; speedup vs baseline: 1.0333x; 1.0333x over previous
//
#include <hip/hip_runtime.h>
#include <hip/hip_bf16.h>

// MetaQDA MAP. D=640, C=64, N=1024, Q=2048, REG=0.3.
// sigma_c*denom = L L^T + U_c J_c U_c^T (rank 18) => Woodbury.
// Round 9: precision hardening of the amplified scalars. f64 Gram + f64 GJ +
// f64 corr; G GEMM = 6-term 3-way-bf16-split MFMA (f32-grade entries);
// in-kernel splitting (no packed buffers), G stored transposed.

#define D 640
#define C 64
#define NSUP 1024
#define Q 2048
#define KMAX 16
#define R18 18           // Woodbury rank: 1 (m) + 16 (x) + 1 (mu)
#define VROWS (C * R18)  // 1152
#define YROWS 3137       // 2048 Xq + 1024 X + 1 m + 64 mu
#define YPAD 3200
#define NEXT 704         // 640 tilde cols + 64 ip0 cols

typedef __attribute__((ext_vector_type(8))) short bf16x8;
typedef __attribute__((ext_vector_type(4))) float floatx4;

__device__ __forceinline__ unsigned short f2bf(float x) {
    unsigned int u = __float_as_uint(x);
    unsigned int r = u + 0x7FFFu + ((u >> 16) & 1u);
    return (unsigned short)(r >> 16);
}
__device__ __forceinline__ void split2(float x, unsigned short& h, unsigned short& l) {
    h = f2bf(x);
    float hf = __uint_as_float((unsigned int)h << 16);
    l = f2bf(x - hf);
}
__device__ __forceinline__ void split3(float x, unsigned short& h, unsigned short& m,
                                       unsigned short& l) {
    h = f2bf(x);
    float hf = __uint_as_float((unsigned int)h << 16);
    float r1 = x - hf;
    m = f2bf(r1);
    float mf = __uint_as_float((unsigned int)m << 16);
    l = f2bf(r1 - mf);
}

// ---------------- setup: DETERMINISTIC class lists, scalars, rowmap ------
__global__ void k_setup(const int* __restrict__ y, const float* __restrict__ kappa,
                        const float* __restrict__ nu, const float* __restrict__ diag,
                        int* __restrict__ cnt, int* __restrict__ idx,
                        float* __restrict__ sc, float* __restrict__ rd,
                        int* __restrict__ rowmap) {
    __shared__ int sidx[C * KMAX];
    __shared__ int lcs[C];
    int tid = threadIdx.x;
    if (tid < C) {
        int k = 0;
        for (int n = 0; n < NSUP; ++n) {          // ordered scan: deterministic
            if (y[n] == tid && k < KMAX) { sidx[tid * KMAX + k] = n; ++k; }
        }
        lcs[tid] = k;
        cnt[tid] = k;
    }
    __syncthreads();
    for (int i = tid; i < C * KMAX; i += 256) idx[i] = sidx[i];
    for (int d = tid; d < D; d += 256) rd[d] = 1.0f / fabsf(diag[d]);
    if (tid < C) {
        int n = lcs[tid];
        float kap = fabsf(kappa[0]) + 1e-6f;
        float nuv = fmaxf(nu[0], (float)(D - 1) + 1e-6f);
        float Ncf = (float)n;
        sc[64 + tid]  = Ncf / (kap + Ncf);            // w_c
        sc[128 + tid] = nuv + Ncf + (float)(D + 2);   // denom_c
        sc[192 + tid] = -1.0f / (kap + Ncf);          // J^{-1} last diag
        if (tid == 0) { sc[0] = kap; sc[1] = nuv; }
    }
    __syncthreads();
    for (int i = tid; i < VROWS; i += 256) {
        int c = i / R18, j = i - c * R18;
        int nc = lcs[c];
        int rm;
        if (j == 0) rm = Q + NSUP;                       // m~
        else if (j <= KMAX) rm = (j - 1 < nc) ? Q + sidx[c * KMAX + j - 1] : -1;
        else rm = Q + NSUP + 1 + c;                      // mu~
        rowmap[i] = rm;
    }
}

// ---------------- mu[c][d] = (1-w)*m + w*mean_c --------------------------
__global__ void k_mu(const float* __restrict__ X, const float* __restrict__ m,
                     const int* __restrict__ cnt, const int* __restrict__ idx,
                     const float* __restrict__ sc, float* __restrict__ mu) {
    int c = blockIdx.x;
    int d = blockIdx.y * 128 + threadIdx.x;
    int n = cnt[c];
    float s = 0.f;
    for (int k = 0; k < n; ++k) s += X[(size_t)idx[c * KMAX + k] * D + d];
    float w = sc[64 + c];
    float mean = (n > 0) ? s / (float)n : 0.f;
    mu[(size_t)c * D + d] = (1.f - w) * m[d] + w * mean;
}

// ---------------- Dinv: invert 5 diagonal 128x128 blocks into Linv -------
__global__ void k_dinv(const float* __restrict__ tlow, const float* __restrict__ rd,
                       float* __restrict__ Linv) {
    __shared__ float Lst[128 * 128];
    int tid = threadIdx.x;
    int b = blockIdx.x >> 5;
    int j = ((blockIdx.x & 31) << 2) + (tid >> 6);
    int lane = tid & 63;
    int bB = b * 128;
    for (int e = tid; e < 128 * 128; e += 256) {
        int c = e & 127, r = e >> 7;
        float v;
        if (r == c) v = 1.0f;
        else if (r > c) v = rd[bB + r] * tlow[(size_t)(bB + r) * D + bB + c];
        else v = 0.f;
        Lst[c * 128 + (r ^ (c & 63))] = v;
    }
    __syncthreads();
    float rd0 = rd[bB + lane], rd1 = rd[bB + 64 + lane];
    float acc0 = 0.f, acc1 = 0.f, zz0 = 0.f, zz1 = 0.f;
    for (int i = j; i < 128; ++i) {
        int ri = i >> 6, il = i & 63;
        float av = (ri == 0) ? acc0 : acc1;
        float ai = __shfl(av, il);
        float zi = (i == j) ? __shfl((ri == 0) ? rd0 : rd1, il) : -ai;
        int sw = i & 63;
        float l0 = Lst[i * 128 + (lane ^ sw)];
        float l1 = Lst[i * 128 + 64 + (lane ^ sw)];
        if (lane > i) acc0 += l0 * zi;
        if (64 + lane > i) acc1 += l1 * zi;
        if (lane == i) zz0 = zi;
        if (64 + lane == i) zz1 = zi;
    }
    Linv[(size_t)(bB + lane) * D + bB + j] = zz0;
    Linv[(size_t)(bB + 64 + lane) * D + bB + j] = zz1;
}

// ---------------- Lhat_ik = Dinv_i * L_ik (strict-lower blocks) ----------
__global__ void k_lhat(const float* __restrict__ tlow, const float* __restrict__ Linv,
                       float* __restrict__ Lhat) {
    const int bi_tab[10] = {1, 2, 2, 3, 3, 3, 4, 4, 4, 4};
    const int bk_tab[10] = {0, 0, 1, 0, 1, 2, 0, 1, 2, 3};
    int p = blockIdx.y;
    int bi = bi_tab[p], bk = bk_tab[p];
    int tid = threadIdx.x;
    int c = tid & 127;
    int r = (blockIdx.x << 1) + (tid >> 7);
    const float* drow = Linv + (size_t)(bi * 128 + r) * D + bi * 128;
    const float* lcol = tlow + (size_t)(bi * 128) * D + bk * 128 + c;
    float s = 0.f;
#pragma unroll 4
    for (int t = 0; t < 128; ++t) s += drow[t] * lcol[(size_t)t * D];
    Lhat[(size_t)(bi * 128 + r) * D + bk * 128 + c] = s;
}

// ---------------- Linv off-diag: fused strip recurrence ------------------
__global__ __launch_bounds__(256) void k_linv_fill(const float* __restrict__ Lhat,
                                                   float* __restrict__ Linv) {
    __shared__ __align__(16) float S[4][128][20];   // 40 KB
    __shared__ __align__(16) float LhT[32][132];    // 17 KB
    int tid = threadIdx.x;
    int b = blockIdx.x >> 3, strip = blockIdx.x & 7;
    int bB = b * 128, cB = bB + strip * 16;
    int ty = tid >> 2, tx = tid & 3;
    {
        int r = tid >> 1, c0 = (tid & 1) * 8;
        const float* src = Linv + (size_t)(bB + r) * D + cB + c0;
#pragma unroll
        for (int e = 0; e < 8; ++e) S[0][r][c0 + e] = src[e];
    }
    __syncthreads();
    for (int i = b + 1; i <= 4; ++i) {
        float acc[2][4] = {};
        for (int j = b; j < i; ++j) {
            for (int k0 = 0; k0 < 128; k0 += 32) {
                __syncthreads();
                {
                    int r = tid >> 1, kk = (tid & 1) * 16;
                    const float* src = Lhat + (size_t)(i * 128 + r) * D + j * 128 + k0 + kk;
#pragma unroll
                    for (int e = 0; e < 16; ++e) LhT[kk + e][r] = src[e];
                }
                __syncthreads();
#pragma unroll 4
                for (int k = 0; k < 32; ++k) {
                    float a0 = LhT[k][ty * 2], a1 = LhT[k][ty * 2 + 1];
                    float4 bv = *(const float4*)&S[j - b][k0 + k][tx * 4];
                    acc[0][0] += a0 * bv.x; acc[0][1] += a0 * bv.y;
                    acc[0][2] += a0 * bv.z; acc[0][3] += a0 * bv.w;
                    acc[1][0] += a1 * bv.x; acc[1][1] += a1 * bv.y;
                    acc[1][2] += a1 * bv.z; acc[1][3] += a1 * bv.w;
                }
            }
        }
        int si = i - b;
#pragma unroll
        for (int rr = 0; rr < 2; ++rr) {
            int r = ty * 2 + rr;
#pragma unroll
            for (int cc = 0; cc < 4; ++cc) {
                float v = -acc[rr][cc];
                if (si <= 3) S[si][r][tx * 4 + cc] = v;
                Linv[(size_t)(i * 128 + r) * D + cB + tx * 4 + cc] = v;
            }
        }
    }
}

// ---------------- Yt GEMM: gather + 2-way split + 3-term MFMA ------------
// Yt[r][0:640] = tilde rows; [640:704] = x_r . mu_c.  A=[Xq;X;m;mu], B=[Linv;mu]
__global__ __launch_bounds__(256) void k_yt(
        const float* __restrict__ Xq, const float* __restrict__ X,
        const float* __restrict__ m, const float* __restrict__ mu,
        const float* __restrict__ Linv, float* __restrict__ Yt) {
    __shared__ unsigned short Ah_s[2048], Al_s[2048], Bh_s[2048], Bl_s[2048];
    int tid = threadIdx.x;
    int rowBase = blockIdx.y * 64, colBase = blockIdx.x * 64;
    int r = tid >> 2, e = (tid & 3) << 3;
    int gr = rowBase + r;
    const float* asrc = nullptr;
    if (gr < Q) asrc = Xq + (size_t)gr * D;
    else if (gr < Q + NSUP) asrc = X + (size_t)(gr - Q) * D;
    else if (gr == Q + NSUP) asrc = m;
    else if (gr < YROWS) asrc = mu + (size_t)(gr - (Q + NSUP + 1)) * D;
    int gc = colBase + r;
    const float* bsrc;
    int bmask;
    if (gc < D) { bsrc = Linv + (size_t)gc * D; bmask = gc; }     // tri mask
    else        { bsrc = mu + (size_t)(gc - D) * D; bmask = 1 << 30; }
    int w = tid >> 6, lane = tid & 63, q = lane >> 4, lr = lane & 15;
    int aoff = (16 * w + lr) * 32 + q * 8;
    floatx4 acc[4] = {{0.f,0.f,0.f,0.f},{0.f,0.f,0.f,0.f},{0.f,0.f,0.f,0.f},{0.f,0.f,0.f,0.f}};
    for (int kk = 0; kk < D; kk += 32) {
        float av[8], bv[8];
        if (asrc) {
            float4 v0 = *(const float4*)(asrc + kk + e);
            float4 v1 = *(const float4*)(asrc + kk + e + 4);
            av[0]=v0.x; av[1]=v0.y; av[2]=v0.z; av[3]=v0.w;
            av[4]=v1.x; av[5]=v1.y; av[6]=v1.z; av[7]=v1.w;
        } else {
#pragma unroll
            for (int i = 0; i < 8; ++i) av[i] = 0.f;
        }
        {
            float4 v0 = *(const float4*)(bsrc + kk + e);
            float4 v1 = *(const float4*)(bsrc + kk + e + 4);
            bv[0]=v0.x; bv[1]=v0.y; bv[2]=v0.z; bv[3]=v0.w;
            bv[4]=v1.x; bv[5]=v1.y; bv[6]=v1.z; bv[7]=v1.w;
#pragma unroll
            for (int i = 0; i < 8; ++i) if (kk + e + i > bmask) bv[i] = 0.f;
        }
        unsigned short ah8[8], al8[8], bh8[8], bl8[8];
#pragma unroll
        for (int i = 0; i < 8; ++i) { split2(av[i], ah8[i], al8[i]); split2(bv[i], bh8[i], bl8[i]); }
        __syncthreads();
#pragma unroll
        for (int i = 0; i < 8; ++i) {
            Ah_s[r * 32 + e + i] = ah8[i]; Al_s[r * 32 + e + i] = al8[i];
            Bh_s[r * 32 + e + i] = bh8[i]; Bl_s[r * 32 + e + i] = bl8[i];
        }
        __syncthreads();
        bf16x8 ah = *(const bf16x8*)(Ah_s + aoff);
        bf16x8 al = *(const bf16x8*)(Al_s + aoff);
#pragma unroll
        for (int tt = 0; tt < 4; ++tt) {
            int boff = (16 * tt + lr) * 32 + q * 8;
            bf16x8 bh = *(const bf16x8*)(Bh_s + boff);
            bf16x8 bl = *(const bf16x8*)(Bl_s + boff);
            acc[tt] = __builtin_amdgcn_mfma_f32_16x16x32_bf16(al, bh, acc[tt], 0, 0, 0);
            acc[tt] = __builtin_amdgcn_mfma_f32_16x16x32_bf16(ah, bl, acc[tt], 0, 0, 0);
            acc[tt] = __builtin_amdgcn_mfma_f32_16x16x32_bf16(ah, bh, acc[tt], 0, 0, 0);
        }
    }
#pragma unroll
    for (int tt = 0; tt < 4; ++tt) {
        int gc2 = colBase + 16 * tt + lr;
#pragma unroll
        for (int rg = 0; rg < 4; ++rg) {
            int gr2 = rowBase + 16 * w + q * 4 + rg;
            if (gr2 < YROWS) Yt[(size_t)gr2 * NEXT + gc2] = acc[tt][rg];
        }
    }
}

// ---------------- G GEMM: 3-way split, 6-term MFMA, transposed out -------
// GT[(c*18+j)*Q + q] = x~q . v~_{c,j}
__global__ __launch_bounds__(256) void k_g6(
        const float* __restrict__ Yt, const int* __restrict__ rowmap,
        float* __restrict__ GT) {
    __shared__ unsigned short Ah_s[2048], Am_s[2048], Al_s[2048];
    __shared__ unsigned short Bh_s[2048], Bm_s[2048], Bl_s[2048];
    int tid = threadIdx.x;
    int rowBase = blockIdx.y * 64, colBase = blockIdx.x * 64;
    int r = tid >> 2, e = (tid & 3) << 3;
    int gr = rowBase + r;                        // < 2048 always
    int gc = colBase + r;                        // < 1152 always
    int br = rowmap[gc];
    const float* asrc = Yt + (size_t)gr * NEXT;
    const float* bsrc = (br >= 0) ? Yt + (size_t)br * NEXT : nullptr;
    int w = tid >> 6, lane = tid & 63, q = lane >> 4, lr = lane & 15;
    int aoff = (16 * w + lr) * 32 + q * 8;
    floatx4 acc[4] = {{0.f,0.f,0.f,0.f},{0.f,0.f,0.f,0.f},{0.f,0.f,0.f,0.f},{0.f,0.f,0.f,0.f}};
    for (int kk = 0; kk < D; kk += 32) {
        float av[8], bv[8];
        {
            float4 v0 = *(const float4*)(asrc + kk + e);
            float4 v1 = *(const float4*)(asrc + kk + e + 4);
            av[0]=v0.x; av[1]=v0.y; av[2]=v0.z; av[3]=v0.w;
            av[4]=v1.x; av[5]=v1.y; av[6]=v1.z; av[7]=v1.w;
        }
        if (bsrc) {
            float4 v0 = *(const float4*)(bsrc + kk + e);
            float4 v1 = *(const float4*)(bsrc + kk + e + 4);
            bv[0]=v0.x; bv[1]=v0.y; bv[2]=v0.z; bv[3]=v0.w;
            bv[4]=v1.x; bv[5]=v1.y; bv[6]=v1.z; bv[7]=v1.w;
        } else {
#pragma unroll
            for (int i = 0; i < 8; ++i) bv[i] = 0.f;
        }
        unsigned short ah8[8], am8[8], al8[8], bh8[8], bm8[8], bl8[8];
#pragma unroll
        for (int i = 0; i < 8; ++i) {
            split3(av[i], ah8[i], am8[i], al8[i]);
            split3(bv[i], bh8[i], bm8[i], bl8[i]);
        }
        __syncthreads();
#pragma unroll
        for (int i = 0; i < 8; ++i) {
            Ah_s[r * 32 + e + i] = ah8[i]; Am_s[r * 32 + e + i] = am8[i]; Al_s[r * 32 + e + i] = al8[i];
            Bh_s[r * 32 + e + i] = bh8[i]; Bm_s[r * 32 + e + i] = bm8[i]; Bl_s[r * 32 + e + i] = bl8[i];
        }
        __syncthreads();
        bf16x8 ah = *(const bf16x8*)(Ah_s + aoff);
        bf16x8 am = *(const bf16x8*)(Am_s + aoff);
        bf16x8 al = *(const bf16x8*)(Al_s + aoff);
#pragma unroll
        for (int tt = 0; tt < 4; ++tt) {
            int boff = (16 * tt + lr) * 32 + q * 8;
            bf16x8 bh = *(const bf16x8*)(Bh_s + boff);
            bf16x8 bm = *(const bf16x8*)(Bm_s + boff);
            bf16x8 bl = *(const bf16x8*)(Bl_s + boff);
            acc[tt] = __builtin_amdgcn_mfma_f32_16x16x32_bf16(al, bh, acc[tt], 0, 0, 0);
            acc[tt] = __builtin_amdgcn_mfma_f32_16x16x32_bf16(ah, bl, acc[tt], 0, 0, 0);
            acc[tt] = __builtin_amdgcn_mfma_f32_16x16x32_bf16(am, bm, acc[tt], 0, 0, 0);
            acc[tt] = __builtin_amdgcn_mfma_f32_16x16x32_bf16(am, bh, acc[tt], 0, 0, 0);
            acc[tt] = __builtin_amdgcn_mfma_f32_16x16x32_bf16(ah, bm, acc[tt], 0, 0, 0);
            acc[tt] = __builtin_amdgcn_mfma_f32_16x16x32_bf16(ah, bh, acc[tt], 0, 0, 0);
        }
    }
#pragma unroll
    for (int tt = 0; tt < 4; ++tt) {
        int gc2 = colBase + 16 * tt + lr;
#pragma unroll
        for (int rg = 0; rg < 4; ++rg) {
            int gr2 = rowBase + 16 * w + q * 4 + rg;
            GT[(size_t)gc2 * Q + gr2] = acc[tt][rg];
        }
    }
}

// ---------------- row norms, f64 accumulate (one wave per row) -----------
__global__ void k_rownorm(const float* __restrict__ A, int ld, double* __restrict__ out) {
    int gw = (blockIdx.x * 256 + threadIdx.x) >> 6;
    int lane = threadIdx.x & 63;
    const float* row = A + (size_t)gw * ld;
    double s = 0.0;
    for (int d = lane; d < D; d += 64) { double v = row[d]; s += v * v; }
#pragma unroll
    for (int off = 32; off; off >>= 1) s += __shfl_xor(s, off);
    if (lane == 0) out[gw] = s;
}

// ---------------- extract ip0 cols (640..703) of Ytout -------------------
__global__ void k_ip0ext(const float* __restrict__ Yt, float* __restrict__ ip0) {
    int gid = blockIdx.x * 256 + threadIdx.x;   // Q*C
    int q = gid >> 6, c = gid & 63;
    ip0[gid] = Yt[(size_t)q * NEXT + D + c];
}

// ---------------- Gram (f64): one wave per (class, pair) -----------------
__global__ __launch_bounds__(256) void k_gram(const float* __restrict__ Yt,
        const int* __restrict__ rowmap, double* __restrict__ gramd,
        float* __restrict__ h, double* __restrict__ btil) {
    int c = blockIdx.x;
    int p = blockIdx.y * 4 + (threadIdx.x >> 6);   // pair 0..170
    int lane = threadIdx.x & 63;
    if (p >= 171) return;
    int i = 0, rem = p;
    while (rem >= R18 - i) { rem -= R18 - i; ++i; }
    int j = i + rem;
    int ri = rowmap[c * R18 + i], rj = rowmap[c * R18 + j];
    double s = 0.0;
    if (ri >= 0 && rj >= 0) {
        const float* a = Yt + (size_t)ri * NEXT;
        const float* b = Yt + (size_t)rj * NEXT;
        for (int d = lane; d < D; d += 64) s += (double)a[d] * (double)b[d];
    }
#pragma unroll
    for (int off = 32; off; off >>= 1) s += __shfl_xor(s, off);
    if (lane == 0) {
        gramd[(size_t)c * R18 * R18 + i * R18 + j] = s;
        if (i != j) gramd[(size_t)c * R18 * R18 + j * R18 + i] = s;
        if (j == R18 - 1) h[c * R18 + i] = (float)s;
        if (i == R18 - 1 && j == R18 - 1) btil[c] = s;
    }
}

// ---------------- per-class 18x18 f64 pivoted GJ (one wave) --------------
__global__ __launch_bounds__(64) void k_inv18(const double* __restrict__ gramd,
        const float* __restrict__ mu, const float* __restrict__ sc,
        float* __restrict__ b0, double* __restrict__ kinvd) {
    __shared__ double aug[R18][2 * R18 + 1];
    __shared__ double fcol[R18];
    int c = blockIdx.x, lane = threadIdx.x;
    for (int e = lane; e < R18 * 2 * R18; e += 64) {
        int i = e / (2 * R18), j = e - i * (2 * R18);
        double v;
        if (j < R18) {
            v = gramd[(size_t)c * R18 * R18 + i * R18 + j];
            if (i == j) {
                if (i == 0) v += 1.0 / (double)sc[0];
                else if (i <= KMAX) v += 1.0;
                else v += (double)sc[192 + c];
            }
        } else v = (j - R18 == i) ? 1.0 : 0.0;
        aug[i][j] = v;
    }
    float s0 = 0.f;
    for (int d = lane; d < D; d += 64) { float v = mu[(size_t)c * D + d]; s0 += v * v; }
#pragma unroll
    for (int off = 32; off; off >>= 1) s0 += __shfl_xor(s0, off);
    if (lane == 0) b0[c] = s0;
    __syncthreads();
    for (int p = 0; p < R18; ++p) {
        double v = (lane >= p && lane < R18) ? fabs(aug[lane][p]) : -1.0;
        int bi = lane;
#pragma unroll
        for (int off = 32; off; off >>= 1) {
            double ov = __shfl_xor(v, off);
            int oi = __shfl_xor(bi, off);
            if (ov > v || (ov == v && oi < bi)) { v = ov; bi = oi; }
        }
        int piv = __shfl(bi, 0);
        __syncthreads();
        if (piv != p && lane < 2 * R18) {
            double t = aug[p][lane]; aug[p][lane] = aug[piv][lane]; aug[piv][lane] = t;
        }
        __syncthreads();
        double rcp = 1.0 / aug[p][p];
        __syncthreads();
        if (lane < 2 * R18) aug[p][lane] *= rcp;
        if (lane < R18) fcol[lane] = aug[lane][p];
        __syncthreads();
        for (int e = lane; e < R18 * 2 * R18; e += 64) {
            int r = e / (2 * R18), j = e - r * (2 * R18);
            if (r != p) aug[r][j] -= fcol[r] * aug[p][j];
        }
        __syncthreads();
    }
    for (int e = lane; e < R18 * R18; e += 64)
        kinvd[(size_t)c * R18 * R18 + e] = aug[e / R18][R18 + e % R18];
}

// ---------------- epilogue (f64 corr) ------------------------------------
__global__ void k_epi(const float* __restrict__ GT, const float* __restrict__ ip0b,
                      const double* __restrict__ at, const double* __restrict__ a0,
                      const float* __restrict__ h, const double* __restrict__ btil,
                      const float* __restrict__ b0, const double* __restrict__ kinvd,
                      const float* __restrict__ sc, float* __restrict__ out) {
    __shared__ double lk[R18 * R18];
    __shared__ float lh[R18];
    __shared__ float ldn_s, lb0;
    __shared__ double lbt;
    int c = blockIdx.x, tid = threadIdx.x;
    for (int i = tid; i < R18 * R18; i += 256) lk[i] = kinvd[(size_t)c * R18 * R18 + i];
    if (tid < R18) lh[tid] = h[c * R18 + tid];
    if (tid == 0) { ldn_s = sc[128 + c]; lbt = btil[c]; lb0 = b0[c]; }
    __syncthreads();
    int q = blockIdx.y * 256 + tid;
    double g[R18];
#pragma unroll
    for (int j = 0; j < R18; ++j)
        g[j] = (double)GT[(size_t)(c * R18 + j) * Q + q];   // coalesced
    double ipt = g[R18 - 1];
#pragma unroll
    for (int j = 0; j < R18; ++j) g[j] -= (double)lh[j];
    double corr = 0.0;
#pragma unroll
    for (int i = 0; i < R18; ++i) {
        double s = 0.0;
#pragma unroll
        for (int j = 0; j < R18; ++j) s += lk[i * R18 + j] * g[j];
        corr += g[i] * s;
    }
    double tt = at[q] - 2.0 * ipt + lbt;
    double t0 = a0[q] - 2.0 * (double)ip0b[(size_t)q * C + c] + (double)lb0;
    out[(size_t)q * C + c] = (float)(-(0.7 * (double)ldn_s * (tt - corr) + 0.3 * t0));
}

extern "C" void kernel_launch(void* const* d_in, const int* in_sizes, int n_in,
                              void* d_out, int out_size, void* d_ws, size_t ws_size,
                              hipStream_t stream) {
    const float* X     = (const float*)d_in[0];
    const int*   y     = (const int*)d_in[1];
    const float* Xq    = (const float*)d_in[2];
    const float* m     = (const float*)d_in[3];
    const float* kappa = (const float*)d_in[4];
    const float* nu    = (const float*)d_in[5];
    const float* tdiag = (const float*)d_in[6];
    const float* tlow  = (const float*)d_in[7];
    float* out = (float*)d_out;

    char* w = (char*)d_ws;
    auto alloc = [&](size_t bytes) {
        char* p = w;
        w += (bytes + 255) & ~(size_t)255;
        return p;
    };
    int*    cnt    = (int*)alloc(C * 4);
    int*    idx    = (int*)alloc(C * KMAX * 4);
    int*    rowmap = (int*)alloc(VROWS * 4);
    float*  sc     = (float*)alloc(256 * 4);
    float*  rd     = (float*)alloc(D * 4);
    float*  mu     = (float*)alloc((size_t)C * D * 4);
    double* at     = (double*)alloc(Q * 8);
    double* a0     = (double*)alloc(Q * 8);
    float*  h      = (float*)alloc(C * R18 * 4);
    double* btil   = (double*)alloc(C * 8);
    float*  b0     = (float*)alloc(C * 4);
    double* gramd  = (double*)alloc((size_t)C * R18 * R18 * 8);   // 166 KB
    double* kinvd  = (double*)alloc((size_t)C * R18 * R18 * 8);   // 166 KB
    float*  ip0b   = (float*)alloc((size_t)Q * C * 4);            // 0.5 MB
    // overlap region: Linv/Lhat dead before GT is written. ~18.5 MB total.
    char* region = alloc((size_t)(9437184 + 9011200));
    float* GT    = (float*)(region);                  // 9,437,184 B (VROWS x Q)
    float* Linv  = (float*)(region);                  // 1,638,400 B
    float* Lhat  = (float*)(region + 1638400);        // 1,638,400 B
    float* Ytout = (float*)(region + 9437184);        // 9,011,200 B (YPAD x NEXT)

    k_setup<<<1, 256, 0, stream>>>(y, kappa, nu, tdiag, cnt, idx, sc, rd, rowmap);
    k_mu<<<dim3(C, D / 128), 128, 0, stream>>>(X, m, cnt, idx, sc, mu);
    k_dinv<<<160, 256, 0, stream>>>(tlow, rd, Linv);
    k_lhat<<<dim3(64, 10), 256, 0, stream>>>(tlow, Linv, Lhat);
    k_linv_fill<<<32, 256, 0, stream>>>(Lhat, Linv);
    k_rownorm<<<Q / 4, 256, 0, stream>>>(Xq, D, a0);
    k_yt<<<dim3(NEXT / 64, (YROWS + 63) / 64), 256, 0, stream>>>(Xq, X, m, mu, Linv, Ytout);
    k_rownorm<<<Q / 4, 256, 0, stream>>>(Ytout, NEXT, at);
    k_gram<<<dim3(C, 43), 256, 0, stream>>>(Ytout, rowmap, gramd, h, btil);
    k_inv18<<<C, 64, 0, stream>>>(gramd, mu, sc, b0, kinvd);
    k_ip0ext<<<(Q * C) / 256, 256, 0, stream>>>(Ytout, ip0b);
    k_g6<<<dim3(VROWS / 64, Q / 64), 256, 0, stream>>>(Ytout, rowmap, GT);
    k_epi<<<dim3(C, Q / 256), 256, 0, stream>>>(GT, ip0b, at, a0, h, btil, b0, kinvd, sc, out);
}

// Round 10
// 393.331 us; speedup vs baseline: 1.0695x; 1.0351x over previous
//
#include <hip/hip_runtime.h>
#include <hip/hip_bf16.h>

// MetaQDA MAP. D=640, C=64, N=1024, Q=2048, REG=0.3.
// sigma_c*denom = L L^T + U_c J_c U_c^T (rank 18) => Woodbury.
// Round 10: k_setup's 64x1024 serial GLOBAL scan (80us latency trap) ->
// stage y in LDS once, scan from LDS (broadcast reads). Identical outputs.

#define D 640
#define C 64
#define NSUP 1024
#define Q 2048
#define KMAX 16
#define R18 18           // Woodbury rank: 1 (m) + 16 (x) + 1 (mu)
#define VROWS (C * R18)  // 1152
#define YROWS 3137       // 2048 Xq + 1024 X + 1 m + 64 mu
#define YPAD 3200
#define NEXT 704         // 640 tilde cols + 64 ip0 cols

typedef __attribute__((ext_vector_type(8))) short bf16x8;
typedef __attribute__((ext_vector_type(4))) float floatx4;

__device__ __forceinline__ unsigned short f2bf(float x) {
    unsigned int u = __float_as_uint(x);
    unsigned int r = u + 0x7FFFu + ((u >> 16) & 1u);
    return (unsigned short)(r >> 16);
}
__device__ __forceinline__ void split2(float x, unsigned short& h, unsigned short& l) {
    h = f2bf(x);
    float hf = __uint_as_float((unsigned int)h << 16);
    l = f2bf(x - hf);
}
__device__ __forceinline__ void split3(float x, unsigned short& h, unsigned short& m,
                                       unsigned short& l) {
    h = f2bf(x);
    float hf = __uint_as_float((unsigned int)h << 16);
    float r1 = x - hf;
    m = f2bf(r1);
    float mf = __uint_as_float((unsigned int)m << 16);
    l = f2bf(r1 - mf);
}

// ---------------- setup: DETERMINISTIC class lists via LDS scan ----------
__global__ void k_setup(const int* __restrict__ y, const float* __restrict__ kappa,
                        const float* __restrict__ nu, const float* __restrict__ diag,
                        int* __restrict__ cnt, int* __restrict__ idx,
                        float* __restrict__ sc, float* __restrict__ rd,
                        int* __restrict__ rowmap) {
    __shared__ int y_s[NSUP];                      // 4 KB
    __shared__ int sidx[C * KMAX];
    __shared__ int lcs[C];
    int tid = threadIdx.x;
    for (int n = tid; n < NSUP; n += 256) y_s[n] = y[n];   // coalesced stage
    __syncthreads();
    if (tid < C) {
        int k = 0;
        for (int n = 0; n < NSUP; ++n) {          // LDS broadcast reads: fast,
            if (y_s[n] == tid && k < KMAX) {      // deterministic ascending order
                sidx[tid * KMAX + k] = n; ++k;
            }
        }
        lcs[tid] = k;
        cnt[tid] = k;
    }
    __syncthreads();
    for (int i = tid; i < C * KMAX; i += 256) idx[i] = sidx[i];
    for (int d = tid; d < D; d += 256) rd[d] = 1.0f / fabsf(diag[d]);
    if (tid < C) {
        int n = lcs[tid];
        float kap = fabsf(kappa[0]) + 1e-6f;
        float nuv = fmaxf(nu[0], (float)(D - 1) + 1e-6f);
        float Ncf = (float)n;
        sc[64 + tid]  = Ncf / (kap + Ncf);            // w_c
        sc[128 + tid] = nuv + Ncf + (float)(D + 2);   // denom_c
        sc[192 + tid] = -1.0f / (kap + Ncf);          // J^{-1} last diag
        if (tid == 0) { sc[0] = kap; sc[1] = nuv; }
    }
    __syncthreads();
    for (int i = tid; i < VROWS; i += 256) {
        int c = i / R18, j = i - c * R18;
        int nc = lcs[c];
        int rm;
        if (j == 0) rm = Q + NSUP;                       // m~
        else if (j <= KMAX) rm = (j - 1 < nc) ? Q + sidx[c * KMAX + j - 1] : -1;
        else rm = Q + NSUP + 1 + c;                      // mu~
        rowmap[i] = rm;
    }
}

// ---------------- mu[c][d] = (1-w)*m + w*mean_c --------------------------
__global__ void k_mu(const float* __restrict__ X, const float* __restrict__ m,
                     const int* __restrict__ cnt, const int* __restrict__ idx,
                     const float* __restrict__ sc, float* __restrict__ mu) {
    int c = blockIdx.x;
    int d = blockIdx.y * 128 + threadIdx.x;
    int n = cnt[c];
    float s = 0.f;
    for (int k = 0; k < n; ++k) s += X[(size_t)idx[c * KMAX + k] * D + d];
    float w = sc[64 + c];
    float mean = (n > 0) ? s / (float)n : 0.f;
    mu[(size_t)c * D + d] = (1.f - w) * m[d] + w * mean;
}

// ---------------- Dinv: invert 5 diagonal 128x128 blocks into Linv -------
__global__ void k_dinv(const float* __restrict__ tlow, const float* __restrict__ rd,
                       float* __restrict__ Linv) {
    __shared__ float Lst[128 * 128];
    int tid = threadIdx.x;
    int b = blockIdx.x >> 5;
    int j = ((blockIdx.x & 31) << 2) + (tid >> 6);
    int lane = tid & 63;
    int bB = b * 128;
    for (int e = tid; e < 128 * 128; e += 256) {
        int c = e & 127, r = e >> 7;
        float v;
        if (r == c) v = 1.0f;
        else if (r > c) v = rd[bB + r] * tlow[(size_t)(bB + r) * D + bB + c];
        else v = 0.f;
        Lst[c * 128 + (r ^ (c & 63))] = v;
    }
    __syncthreads();
    float rd0 = rd[bB + lane], rd1 = rd[bB + 64 + lane];
    float acc0 = 0.f, acc1 = 0.f, zz0 = 0.f, zz1 = 0.f;
    for (int i = j; i < 128; ++i) {
        int ri = i >> 6, il = i & 63;
        float av = (ri == 0) ? acc0 : acc1;
        float ai = __shfl(av, il);
        float zi = (i == j) ? __shfl((ri == 0) ? rd0 : rd1, il) : -ai;
        int sw = i & 63;
        float l0 = Lst[i * 128 + (lane ^ sw)];
        float l1 = Lst[i * 128 + 64 + (lane ^ sw)];
        if (lane > i) acc0 += l0 * zi;
        if (64 + lane > i) acc1 += l1 * zi;
        if (lane == i) zz0 = zi;
        if (64 + lane == i) zz1 = zi;
    }
    Linv[(size_t)(bB + lane) * D + bB + j] = zz0;
    Linv[(size_t)(bB + 64 + lane) * D + bB + j] = zz1;
}

// ---------------- Lhat_ik = Dinv_i * L_ik (strict-lower blocks) ----------
__global__ void k_lhat(const float* __restrict__ tlow, const float* __restrict__ Linv,
                       float* __restrict__ Lhat) {
    const int bi_tab[10] = {1, 2, 2, 3, 3, 3, 4, 4, 4, 4};
    const int bk_tab[10] = {0, 0, 1, 0, 1, 2, 0, 1, 2, 3};
    int p = blockIdx.y;
    int bi = bi_tab[p], bk = bk_tab[p];
    int tid = threadIdx.x;
    int c = tid & 127;
    int r = (blockIdx.x << 1) + (tid >> 7);
    const float* drow = Linv + (size_t)(bi * 128 + r) * D + bi * 128;
    const float* lcol = tlow + (size_t)(bi * 128) * D + bk * 128 + c;
    float s = 0.f;
#pragma unroll 4
    for (int t = 0; t < 128; ++t) s += drow[t] * lcol[(size_t)t * D];
    Lhat[(size_t)(bi * 128 + r) * D + bk * 128 + c] = s;
}

// ---------------- Linv off-diag: fused strip recurrence ------------------
__global__ __launch_bounds__(256) void k_linv_fill(const float* __restrict__ Lhat,
                                                   float* __restrict__ Linv) {
    __shared__ __align__(16) float S[4][128][20];   // 40 KB
    __shared__ __align__(16) float LhT[32][132];    // 17 KB
    int tid = threadIdx.x;
    int b = blockIdx.x >> 3, strip = blockIdx.x & 7;
    int bB = b * 128, cB = bB + strip * 16;
    int ty = tid >> 2, tx = tid & 3;
    {
        int r = tid >> 1, c0 = (tid & 1) * 8;
        const float* src = Linv + (size_t)(bB + r) * D + cB + c0;
#pragma unroll
        for (int e = 0; e < 8; ++e) S[0][r][c0 + e] = src[e];
    }
    __syncthreads();
    for (int i = b + 1; i <= 4; ++i) {
        float acc[2][4] = {};
        for (int j = b; j < i; ++j) {
            for (int k0 = 0; k0 < 128; k0 += 32) {
                __syncthreads();
                {
                    int r = tid >> 1, kk = (tid & 1) * 16;
                    const float* src = Lhat + (size_t)(i * 128 + r) * D + j * 128 + k0 + kk;
#pragma unroll
                    for (int e = 0; e < 16; ++e) LhT[kk + e][r] = src[e];
                }
                __syncthreads();
#pragma unroll 4
                for (int k = 0; k < 32; ++k) {
                    float a0 = LhT[k][ty * 2], a1 = LhT[k][ty * 2 + 1];
                    float4 bv = *(const float4*)&S[j - b][k0 + k][tx * 4];
                    acc[0][0] += a0 * bv.x; acc[0][1] += a0 * bv.y;
                    acc[0][2] += a0 * bv.z; acc[0][3] += a0 * bv.w;
                    acc[1][0] += a1 * bv.x; acc[1][1] += a1 * bv.y;
                    acc[1][2] += a1 * bv.z; acc[1][3] += a1 * bv.w;
                }
            }
        }
        int si = i - b;
#pragma unroll
        for (int rr = 0; rr < 2; ++rr) {
            int r = ty * 2 + rr;
#pragma unroll
            for (int cc = 0; cc < 4; ++cc) {
                float v = -acc[rr][cc];
                if (si <= 3) S[si][r][tx * 4 + cc] = v;
                Linv[(size_t)(i * 128 + r) * D + cB + tx * 4 + cc] = v;
            }
        }
    }
}

// ---------------- Yt GEMM: gather + 2-way split + 3-term MFMA ------------
// Yt[r][0:640] = tilde rows; [640:704] = x_r . mu_c.  A=[Xq;X;m;mu], B=[Linv;mu]
__global__ __launch_bounds__(256) void k_yt(
        const float* __restrict__ Xq, const float* __restrict__ X,
        const float* __restrict__ m, const float* __restrict__ mu,
        const float* __restrict__ Linv, float* __restrict__ Yt) {
    __shared__ unsigned short Ah_s[2048], Al_s[2048], Bh_s[2048], Bl_s[2048];
    int tid = threadIdx.x;
    int rowBase = blockIdx.y * 64, colBase = blockIdx.x * 64;
    int r = tid >> 2, e = (tid & 3) << 3;
    int gr = rowBase + r;
    const float* asrc = nullptr;
    if (gr < Q) asrc = Xq + (size_t)gr * D;
    else if (gr < Q + NSUP) asrc = X + (size_t)(gr - Q) * D;
    else if (gr == Q + NSUP) asrc = m;
    else if (gr < YROWS) asrc = mu + (size_t)(gr - (Q + NSUP + 1)) * D;
    int gc = colBase + r;
    const float* bsrc;
    int bmask;
    if (gc < D) { bsrc = Linv + (size_t)gc * D; bmask = gc; }     // tri mask
    else        { bsrc = mu + (size_t)(gc - D) * D; bmask = 1 << 30; }
    int w = tid >> 6, lane = tid & 63, q = lane >> 4, lr = lane & 15;
    int aoff = (16 * w + lr) * 32 + q * 8;
    floatx4 acc[4] = {{0.f,0.f,0.f,0.f},{0.f,0.f,0.f,0.f},{0.f,0.f,0.f,0.f},{0.f,0.f,0.f,0.f}};
    for (int kk = 0; kk < D; kk += 32) {
        float av[8], bv[8];
        if (asrc) {
            float4 v0 = *(const float4*)(asrc + kk + e);
            float4 v1 = *(const float4*)(asrc + kk + e + 4);
            av[0]=v0.x; av[1]=v0.y; av[2]=v0.z; av[3]=v0.w;
            av[4]=v1.x; av[5]=v1.y; av[6]=v1.z; av[7]=v1.w;
        } else {
#pragma unroll
            for (int i = 0; i < 8; ++i) av[i] = 0.f;
        }
        {
            float4 v0 = *(const float4*)(bsrc + kk + e);
            float4 v1 = *(const float4*)(bsrc + kk + e + 4);
            bv[0]=v0.x; bv[1]=v0.y; bv[2]=v0.z; bv[3]=v0.w;
            bv[4]=v1.x; bv[5]=v1.y; bv[6]=v1.z; bv[7]=v1.w;
#pragma unroll
            for (int i = 0; i < 8; ++i) if (kk + e + i > bmask) bv[i] = 0.f;
        }
        unsigned short ah8[8], al8[8], bh8[8], bl8[8];
#pragma unroll
        for (int i = 0; i < 8; ++i) { split2(av[i], ah8[i], al8[i]); split2(bv[i], bh8[i], bl8[i]); }
        __syncthreads();
#pragma unroll
        for (int i = 0; i < 8; ++i) {
            Ah_s[r * 32 + e + i] = ah8[i]; Al_s[r * 32 + e + i] = al8[i];
            Bh_s[r * 32 + e + i] = bh8[i]; Bl_s[r * 32 + e + i] = bl8[i];
        }
        __syncthreads();
        bf16x8 ah = *(const bf16x8*)(Ah_s + aoff);
        bf16x8 al = *(const bf16x8*)(Al_s + aoff);
#pragma unroll
        for (int tt = 0; tt < 4; ++tt) {
            int boff = (16 * tt + lr) * 32 + q * 8;
            bf16x8 bh = *(const bf16x8*)(Bh_s + boff);
            bf16x8 bl = *(const bf16x8*)(Bl_s + boff);
            acc[tt] = __builtin_amdgcn_mfma_f32_16x16x32_bf16(al, bh, acc[tt], 0, 0, 0);
            acc[tt] = __builtin_amdgcn_mfma_f32_16x16x32_bf16(ah, bl, acc[tt], 0, 0, 0);
            acc[tt] = __builtin_amdgcn_mfma_f32_16x16x32_bf16(ah, bh, acc[tt], 0, 0, 0);
        }
    }
#pragma unroll
    for (int tt = 0; tt < 4; ++tt) {
        int gc2 = colBase + 16 * tt + lr;
#pragma unroll
        for (int rg = 0; rg < 4; ++rg) {
            int gr2 = rowBase + 16 * w + q * 4 + rg;
            if (gr2 < YROWS) Yt[(size_t)gr2 * NEXT + gc2] = acc[tt][rg];
        }
    }
}

// ---------------- G GEMM: 3-way split, 6-term MFMA, transposed out -------
// GT[(c*18+j)*Q + q] = x~q . v~_{c,j}
__global__ __launch_bounds__(256) void k_g6(
        const float* __restrict__ Yt, const int* __restrict__ rowmap,
        float* __restrict__ GT) {
    __shared__ unsigned short Ah_s[2048], Am_s[2048], Al_s[2048];
    __shared__ unsigned short Bh_s[2048], Bm_s[2048], Bl_s[2048];
    int tid = threadIdx.x;
    int rowBase = blockIdx.y * 64, colBase = blockIdx.x * 64;
    int r = tid >> 2, e = (tid & 3) << 3;
    int gr = rowBase + r;                        // < 2048 always
    int gc = colBase + r;                        // < 1152 always
    int br = rowmap[gc];
    const float* asrc = Yt + (size_t)gr * NEXT;
    const float* bsrc = (br >= 0) ? Yt + (size_t)br * NEXT : nullptr;
    int w = tid >> 6, lane = tid & 63, q = lane >> 4, lr = lane & 15;
    int aoff = (16 * w + lr) * 32 + q * 8;
    floatx4 acc[4] = {{0.f,0.f,0.f,0.f},{0.f,0.f,0.f,0.f},{0.f,0.f,0.f,0.f},{0.f,0.f,0.f,0.f}};
    for (int kk = 0; kk < D; kk += 32) {
        float av[8], bv[8];
        {
            float4 v0 = *(const float4*)(asrc + kk + e);
            float4 v1 = *(const float4*)(asrc + kk + e + 4);
            av[0]=v0.x; av[1]=v0.y; av[2]=v0.z; av[3]=v0.w;
            av[4]=v1.x; av[5]=v1.y; av[6]=v1.z; av[7]=v1.w;
        }
        if (bsrc) {
            float4 v0 = *(const float4*)(bsrc + kk + e);
            float4 v1 = *(const float4*)(bsrc + kk + e + 4);
            bv[0]=v0.x; bv[1]=v0.y; bv[2]=v0.z; bv[3]=v0.w;
            bv[4]=v1.x; bv[5]=v1.y; bv[6]=v1.z; bv[7]=v1.w;
        } else {
#pragma unroll
            for (int i = 0; i < 8; ++i) bv[i] = 0.f;
        }
        unsigned short ah8[8], am8[8], al8[8], bh8[8], bm8[8], bl8[8];
#pragma unroll
        for (int i = 0; i < 8; ++i) {
            split3(av[i], ah8[i], am8[i], al8[i]);
            split3(bv[i], bh8[i], bm8[i], bl8[i]);
        }
        __syncthreads();
#pragma unroll
        for (int i = 0; i < 8; ++i) {
            Ah_s[r * 32 + e + i] = ah8[i]; Am_s[r * 32 + e + i] = am8[i]; Al_s[r * 32 + e + i] = al8[i];
            Bh_s[r * 32 + e + i] = bh8[i]; Bm_s[r * 32 + e + i] = bm8[i]; Bl_s[r * 32 + e + i] = bl8[i];
        }
        __syncthreads();
        bf16x8 ah = *(const bf16x8*)(Ah_s + aoff);
        bf16x8 am = *(const bf16x8*)(Am_s + aoff);
        bf16x8 al = *(const bf16x8*)(Al_s + aoff);
#pragma unroll
        for (int tt = 0; tt < 4; ++tt) {
            int boff = (16 * tt + lr) * 32 + q * 8;
            bf16x8 bh = *(const bf16x8*)(Bh_s + boff);
            bf16x8 bm = *(const bf16x8*)(Bm_s + boff);
            bf16x8 bl = *(const bf16x8*)(Bl_s + boff);
            acc[tt] = __builtin_amdgcn_mfma_f32_16x16x32_bf16(al, bh, acc[tt], 0, 0, 0);
            acc[tt] = __builtin_amdgcn_mfma_f32_16x16x32_bf16(ah, bl, acc[tt], 0, 0, 0);
            acc[tt] = __builtin_amdgcn_mfma_f32_16x16x32_bf16(am, bm, acc[tt], 0, 0, 0);
            acc[tt] = __builtin_amdgcn_mfma_f32_16x16x32_bf16(am, bh, acc[tt], 0, 0, 0);
            acc[tt] = __builtin_amdgcn_mfma_f32_16x16x32_bf16(ah, bm, acc[tt], 0, 0, 0);
            acc[tt] = __builtin_amdgcn_mfma_f32_16x16x32_bf16(ah, bh, acc[tt], 0, 0, 0);
        }
    }
#pragma unroll
    for (int tt = 0; tt < 4; ++tt) {
        int gc2 = colBase + 16 * tt + lr;
#pragma unroll
        for (int rg = 0; rg < 4; ++rg) {
            int gr2 = rowBase + 16 * w + q * 4 + rg;
            GT[(size_t)gc2 * Q + gr2] = acc[tt][rg];
        }
    }
}

// ---------------- row norms, f64 accumulate (one wave per row) -----------
__global__ void k_rownorm(const float* __restrict__ A, int ld, double* __restrict__ out) {
    int gw = (blockIdx.x * 256 + threadIdx.x) >> 6;
    int lane = threadIdx.x & 63;
    const float* row = A + (size_t)gw * ld;
    double s = 0.0;
    for (int d = lane; d < D; d += 64) { double v = row[d]; s += v * v; }
#pragma unroll
    for (int off = 32; off; off >>= 1) s += __shfl_xor(s, off);
    if (lane == 0) out[gw] = s;
}

// ---------------- extract ip0 cols (640..703) of Ytout -------------------
__global__ void k_ip0ext(const float* __restrict__ Yt, float* __restrict__ ip0) {
    int gid = blockIdx.x * 256 + threadIdx.x;   // Q*C
    int q = gid >> 6, c = gid & 63;
    ip0[gid] = Yt[(size_t)q * NEXT + D + c];
}

// ---------------- Gram (f64): one wave per (class, pair) -----------------
__global__ __launch_bounds__(256) void k_gram(const float* __restrict__ Yt,
        const int* __restrict__ rowmap, double* __restrict__ gramd,
        float* __restrict__ h, double* __restrict__ btil) {
    int c = blockIdx.x;
    int p = blockIdx.y * 4 + (threadIdx.x >> 6);   // pair 0..170
    int lane = threadIdx.x & 63;
    if (p >= 171) return;
    int i = 0, rem = p;
    while (rem >= R18 - i) { rem -= R18 - i; ++i; }
    int j = i + rem;
    int ri = rowmap[c * R18 + i], rj = rowmap[c * R18 + j];
    double s = 0.0;
    if (ri >= 0 && rj >= 0) {
        const float* a = Yt + (size_t)ri * NEXT;
        const float* b = Yt + (size_t)rj * NEXT;
        for (int d = lane; d < D; d += 64) s += (double)a[d] * (double)b[d];
    }
#pragma unroll
    for (int off = 32; off; off >>= 1) s += __shfl_xor(s, off);
    if (lane == 0) {
        gramd[(size_t)c * R18 * R18 + i * R18 + j] = s;
        if (i != j) gramd[(size_t)c * R18 * R18 + j * R18 + i] = s;
        if (j == R18 - 1) h[c * R18 + i] = (float)s;
        if (i == R18 - 1 && j == R18 - 1) btil[c] = s;
    }
}

// ---------------- per-class 18x18 f64 pivoted GJ (one wave) --------------
__global__ __launch_bounds__(64) void k_inv18(const double* __restrict__ gramd,
        const float* __restrict__ mu, const float* __restrict__ sc,
        float* __restrict__ b0, double* __restrict__ kinvd) {
    __shared__ double aug[R18][2 * R18 + 1];
    __shared__ double fcol[R18];
    int c = blockIdx.x, lane = threadIdx.x;
    for (int e = lane; e < R18 * 2 * R18; e += 64) {
        int i = e / (2 * R18), j = e - i * (2 * R18);
        double v;
        if (j < R18) {
            v = gramd[(size_t)c * R18 * R18 + i * R18 + j];
            if (i == j) {
                if (i == 0) v += 1.0 / (double)sc[0];
                else if (i <= KMAX) v += 1.0;
                else v += (double)sc[192 + c];
            }
        } else v = (j - R18 == i) ? 1.0 : 0.0;
        aug[i][j] = v;
    }
    float s0 = 0.f;
    for (int d = lane; d < D; d += 64) { float v = mu[(size_t)c * D + d]; s0 += v * v; }
#pragma unroll
    for (int off = 32; off; off >>= 1) s0 += __shfl_xor(s0, off);
    if (lane == 0) b0[c] = s0;
    __syncthreads();
    for (int p = 0; p < R18; ++p) {
        double v = (lane >= p && lane < R18) ? fabs(aug[lane][p]) : -1.0;
        int bi = lane;
#pragma unroll
        for (int off = 32; off; off >>= 1) {
            double ov = __shfl_xor(v, off);
            int oi = __shfl_xor(bi, off);
            if (ov > v || (ov == v && oi < bi)) { v = ov; bi = oi; }
        }
        int piv = __shfl(bi, 0);
        __syncthreads();
        if (piv != p && lane < 2 * R18) {
            double t = aug[p][lane]; aug[p][lane] = aug[piv][lane]; aug[piv][lane] = t;
        }
        __syncthreads();
        double rcp = 1.0 / aug[p][p];
        __syncthreads();
        if (lane < 2 * R18) aug[p][lane] *= rcp;
        if (lane < R18) fcol[lane] = aug[lane][p];
        __syncthreads();
        for (int e = lane; e < R18 * 2 * R18; e += 64) {
            int r = e / (2 * R18), j = e - r * (2 * R18);
            if (r != p) aug[r][j] -= fcol[r] * aug[p][j];
        }
        __syncthreads();
    }
    for (int e = lane; e < R18 * R18; e += 64)
        kinvd[(size_t)c * R18 * R18 + e] = aug[e / R18][R18 + e % R18];
}

// ---------------- epilogue (f64 corr) ------------------------------------
__global__ void k_epi(const float* __restrict__ GT, const float* __restrict__ ip0b,
                      const double* __restrict__ at, const double* __restrict__ a0,
                      const float* __restrict__ h, const double* __restrict__ btil,
                      const float* __restrict__ b0, const double* __restrict__ kinvd,
                      const float* __restrict__ sc, float* __restrict__ out) {
    __shared__ double lk[R18 * R18];
    __shared__ float lh[R18];
    __shared__ float ldn_s, lb0;
    __shared__ double lbt;
    int c = blockIdx.x, tid = threadIdx.x;
    for (int i = tid; i < R18 * R18; i += 256) lk[i] = kinvd[(size_t)c * R18 * R18 + i];
    if (tid < R18) lh[tid] = h[c * R18 + tid];
    if (tid == 0) { ldn_s = sc[128 + c]; lbt = btil[c]; lb0 = b0[c]; }
    __syncthreads();
    int q = blockIdx.y * 256 + tid;
    double g[R18];
#pragma unroll
    for (int j = 0; j < R18; ++j)
        g[j] = (double)GT[(size_t)(c * R18 + j) * Q + q];   // coalesced
    double ipt = g[R18 - 1];
#pragma unroll
    for (int j = 0; j < R18; ++j) g[j] -= (double)lh[j];
    double corr = 0.0;
#pragma unroll
    for (int i = 0; i < R18; ++i) {
        double s = 0.0;
#pragma unroll
        for (int j = 0; j < R18; ++j) s += lk[i * R18 + j] * g[j];
        corr += g[i] * s;
    }
    double tt = at[q] - 2.0 * ipt + lbt;
    double t0 = a0[q] - 2.0 * (double)ip0b[(size_t)q * C + c] + (double)lb0;
    out[(size_t)q * C + c] = (float)(-(0.7 * (double)ldn_s * (tt - corr) + 0.3 * t0));
}

extern "C" void kernel_launch(void* const* d_in, const int* in_sizes, int n_in,
                              void* d_out, int out_size, void* d_ws, size_t ws_size,
                              hipStream_t stream) {
    const float* X     = (const float*)d_in[0];
    const int*   y     = (const int*)d_in[1];
    const float* Xq    = (const float*)d_in[2];
    const float* m     = (const float*)d_in[3];
    const float* kappa = (const float*)d_in[4];
    const float* nu    = (const float*)d_in[5];
    const float* tdiag = (const float*)d_in[6];
    const float* tlow  = (const float*)d_in[7];
    float* out = (float*)d_out;

    char* w = (char*)d_ws;
    auto alloc = [&](size_t bytes) {
        char* p = w;
        w += (bytes + 255) & ~(size_t)255;
        return p;
    };
    int*    cnt    = (int*)alloc(C * 4);
    int*    idx    = (int*)alloc(C * KMAX * 4);
    int*    rowmap = (int*)alloc(VROWS * 4);
    float*  sc     = (float*)alloc(256 * 4);
    float*  rd     = (float*)alloc(D * 4);
    float*  mu     = (float*)alloc((size_t)C * D * 4);
    double* at     = (double*)alloc(Q * 8);
    double* a0     = (double*)alloc(Q * 8);
    float*  h      = (float*)alloc(C * R18 * 4);
    double* btil   = (double*)alloc(C * 8);
    float*  b0     = (float*)alloc(C * 4);
    double* gramd  = (double*)alloc((size_t)C * R18 * R18 * 8);   // 166 KB
    double* kinvd  = (double*)alloc((size_t)C * R18 * R18 * 8);   // 166 KB
    float*  ip0b   = (float*)alloc((size_t)Q * C * 4);            // 0.5 MB
    // overlap region: Linv/Lhat dead before GT is written. ~18.5 MB total.
    char* region = alloc((size_t)(9437184 + 9011200));
    float* GT    = (float*)(region);                  // 9,437,184 B (VROWS x Q)
    float* Linv  = (float*)(region);                  // 1,638,400 B
    float* Lhat  = (float*)(region + 1638400);        // 1,638,400 B
    float* Ytout = (float*)(region + 9437184);        // 9,011,200 B (YPAD x NEXT)

    k_setup<<<1, 256, 0, stream>>>(y, kappa, nu, tdiag, cnt, idx, sc, rd, rowmap);
    k_mu<<<dim3(C, D / 128), 128, 0, stream>>>(X, m, cnt, idx, sc, mu);
    k_dinv<<<160, 256, 0, stream>>>(tlow, rd, Linv);
    k_lhat<<<dim3(64, 10), 256, 0, stream>>>(tlow, Linv, Lhat);
    k_linv_fill<<<32, 256, 0, stream>>>(Lhat, Linv);
    k_rownorm<<<Q / 4, 256, 0, stream>>>(Xq, D, a0);
    k_yt<<<dim3(NEXT / 64, (YROWS + 63) / 64), 256, 0, stream>>>(Xq, X, m, mu, Linv, Ytout);
    k_rownorm<<<Q / 4, 256, 0, stream>>>(Ytout, NEXT, at);
    k_gram<<<dim3(C, 43), 256, 0, stream>>>(Ytout, rowmap, gramd, h, btil);
    k_inv18<<<C, 64, 0, stream>>>(gramd, mu, sc, b0, kinvd);
    k_ip0ext<<<(Q * C) / 256, 256, 0, stream>>>(Ytout, ip0b);
    k_g6<<<dim3(VROWS / 64, Q / 64), 256, 0, stream>>>(Ytout, rowmap, GT);
    k_epi<<<dim3(C, Q / 256), 256, 0, stream>>>(GT, ip0b, at, a0, h, btil, b0, kinvd, sc, out);
}